// Round 1
// baseline (81.746 us; speedup 1.0000x reference)
//
#include <hip/hip_runtime.h>

// y = sigmoid(x)*h + (1-sigmoid(x))*tanh(x)
// Memory-bound elementwise: float4 vectorized, grid-stride.

__global__ __launch_bounds__(256) void pseudo_mamba_kernel(
    const float4* __restrict__ x4,
    const float4* __restrict__ h4,
    float4* __restrict__ y4,
    int n4)
{
    int idx = blockIdx.x * blockDim.x + threadIdx.x;
    int stride = gridDim.x * blockDim.x;
    for (int i = idx; i < n4; i += stride) {
        float4 xv = x4[i];
        float4 hv = h4[i];
        float4 yv;
        const float* xp = reinterpret_cast<const float*>(&xv);
        const float* hp = reinterpret_cast<const float*>(&hv);
        float* yp = reinterpret_cast<float*>(&yv);
#pragma unroll
        for (int j = 0; j < 4; ++j) {
            float xx = xp[j];
            // clamp so exp(-x) can't overflow; tanh/sigmoid saturated past +-15
            xx = fminf(fmaxf(xx, -15.0f), 15.0f);
            float e  = __expf(-xx);         // e = exp(-x)
            float g  = 1.0f / (1.0f + e);   // sigmoid(x)
            float e2 = e * e;               // exp(-2x)
            float t  = (1.0f - e2) / (1.0f + e2);  // tanh(x)
            yp[j] = g * hp[j] + (1.0f - g) * t;
        }
        y4[i] = yv;
    }
}

extern "C" void kernel_launch(void* const* d_in, const int* in_sizes, int n_in,
                              void* d_out, int out_size, void* d_ws, size_t ws_size,
                              hipStream_t stream) {
    const float4* x4 = reinterpret_cast<const float4*>(d_in[0]);
    const float4* h4 = reinterpret_cast<const float4*>(d_in[1]);
    float4* y4 = reinterpret_cast<float4*>(d_out);
    int n = in_sizes[0];           // 8192*4096, divisible by 4
    int n4 = n >> 2;
    int block = 256;
    int grid = 2048;               // 256 CU x 8 blocks/CU; grid-stride covers rest
    pseudo_mamba_kernel<<<grid, block, 0, stream>>>(x4, h4, y4, n4);
}

// Round 3
// 63.926 us; speedup vs baseline: 1.2788x; 1.2788x over previous
//
#include <hip/hip_runtime.h>

// y = sigmoid(x)*h + (1-sigmoid(x))*tanh(x)
// Memory-bound elementwise. Levers: rcp intrinsics (no full-precision divide),
// unroll-4 for memory-level parallelism, non-temporal store (y never re-read;
// keep L3 for x/h which together exactly fit the 256 MiB Infinity Cache).

#define UNROLL 4

typedef float f32x4 __attribute__((ext_vector_type(4)));

__device__ __forceinline__ float mamba_elem(float xx, float hh) {
    // clamp so exp(-2x) can't overflow; sigmoid/tanh saturated past +-15
    xx = fminf(fmaxf(xx, -15.0f), 15.0f);
    float e  = __expf(-xx);                          // exp(-x)
    float e2 = e * e;                                // exp(-2x)
    float g  = __builtin_amdgcn_rcpf(1.0f + e);      // sigmoid(x)
    float r2 = __builtin_amdgcn_rcpf(1.0f + e2);
    float t  = __builtin_fmaf(2.0f, r2, -1.0f);      // tanh(x) = 2/(1+e2)-1
    float omg = e * g;                               // 1 - g
    return __builtin_fmaf(g, hh, omg * t);
}

__global__ __launch_bounds__(256) void pseudo_mamba_kernel(
    const f32x4* __restrict__ x4,
    const f32x4* __restrict__ h4,
    f32x4* __restrict__ y4,
    int n4)
{
    int base = blockIdx.x * (256 * UNROLL) + threadIdx.x;

    f32x4 xv[UNROLL], hv[UNROLL];
    bool ok[UNROLL];
#pragma unroll
    for (int u = 0; u < UNROLL; ++u) {
        int i = base + u * 256;
        ok[u] = (i < n4);
        if (ok[u]) { xv[u] = x4[i]; hv[u] = h4[i]; }
    }
#pragma unroll
    for (int u = 0; u < UNROLL; ++u) {
        if (!ok[u]) continue;
        f32x4 yv;
        yv.x = mamba_elem(xv[u].x, hv[u].x);
        yv.y = mamba_elem(xv[u].y, hv[u].y);
        yv.z = mamba_elem(xv[u].z, hv[u].z);
        yv.w = mamba_elem(xv[u].w, hv[u].w);
        __builtin_nontemporal_store(yv, &y4[base + u * 256]);
    }
}

extern "C" void kernel_launch(void* const* d_in, const int* in_sizes, int n_in,
                              void* d_out, int out_size, void* d_ws, size_t ws_size,
                              hipStream_t stream) {
    const f32x4* x4 = reinterpret_cast<const f32x4*>(d_in[0]);
    const f32x4* h4 = reinterpret_cast<const f32x4*>(d_in[1]);
    f32x4* y4 = reinterpret_cast<f32x4*>(d_out);
    int n = in_sizes[0];                 // 8192*4096
    int n4 = n >> 2;                     // float4 count
    int per_block = 256 * UNROLL;
    int grid = (n4 + per_block - 1) / per_block;   // 8192 blocks, exact fit
    pseudo_mamba_kernel<<<grid, 256, 0, stream>>>(x4, h4, y4, n4);
}

// Round 4
// 61.736 us; speedup vs baseline: 1.3241x; 1.0355x over previous
//
#include <hip/hip_runtime.h>

// y = sigmoid(x)*h + (1-sigmoid(x))*tanh(x)
// Memory-bound elementwise. rcp intrinsics, unroll-8 MLP, NT stores,
// exact-fit specialization (no per-iteration bounds checks).

#define UNROLL 8

typedef float f32x4 __attribute__((ext_vector_type(4)));

__device__ __forceinline__ float mamba_elem(float xx, float hh) {
    // clamp so exp(-2x) can't overflow; sigmoid/tanh saturated past +-15
    xx = fminf(fmaxf(xx, -15.0f), 15.0f);
    float e  = __expf(-xx);                          // exp(-x)
    float e2 = e * e;                                // exp(-2x)
    float g  = __builtin_amdgcn_rcpf(1.0f + e);      // sigmoid(x)
    float r2 = __builtin_amdgcn_rcpf(1.0f + e2);
    float t  = __builtin_fmaf(2.0f, r2, -1.0f);      // tanh(x) = 2/(1+e2)-1
    float omg = e * g;                               // 1 - g
    return __builtin_fmaf(g, hh, omg * t);
}

template <bool EXACT>
__global__ __launch_bounds__(256) void pseudo_mamba_kernel(
    const f32x4* __restrict__ x4,
    const f32x4* __restrict__ h4,
    f32x4* __restrict__ y4,
    int n4)
{
    int base = blockIdx.x * (256 * UNROLL) + threadIdx.x;

    f32x4 xv[UNROLL], hv[UNROLL];
#pragma unroll
    for (int u = 0; u < UNROLL; ++u) {
        int i = base + u * 256;
        if (EXACT || i < n4) { xv[u] = x4[i]; hv[u] = h4[i]; }
    }
#pragma unroll
    for (int u = 0; u < UNROLL; ++u) {
        int i = base + u * 256;
        if (!EXACT && i >= n4) continue;
        f32x4 yv;
        yv.x = mamba_elem(xv[u].x, hv[u].x);
        yv.y = mamba_elem(xv[u].y, hv[u].y);
        yv.z = mamba_elem(xv[u].z, hv[u].z);
        yv.w = mamba_elem(xv[u].w, hv[u].w);
        __builtin_nontemporal_store(yv, &y4[i]);
    }
}

extern "C" void kernel_launch(void* const* d_in, const int* in_sizes, int n_in,
                              void* d_out, int out_size, void* d_ws, size_t ws_size,
                              hipStream_t stream) {
    const f32x4* x4 = reinterpret_cast<const f32x4*>(d_in[0]);
    const f32x4* h4 = reinterpret_cast<const f32x4*>(d_in[1]);
    f32x4* y4 = reinterpret_cast<f32x4*>(d_out);
    int n = in_sizes[0];                 // 8192*4096
    int n4 = n >> 2;                     // float4 count
    int per_block = 256 * UNROLL;        // 2048
    int grid = (n4 + per_block - 1) / per_block;
    if (n4 % per_block == 0) {
        pseudo_mamba_kernel<true><<<grid, 256, 0, stream>>>(x4, h4, y4, n4);
    } else {
        pseudo_mamba_kernel<false><<<grid, 256, 0, stream>>>(x4, h4, y4, n4);
    }
}